// Round 5
// baseline (494.625 us; speedup 1.0000x reference)
//
#include <hip/hip_runtime.h>
#include <hip/hip_bf16.h>

typedef unsigned short u16;
typedef unsigned int   u32;
typedef _Float16 f16;
typedef __attribute__((ext_vector_type(8))) _Float16 f16x8;
typedef __attribute__((ext_vector_type(4))) _Float16 f16x4;
typedef __attribute__((ext_vector_type(4))) float    f32x4;
typedef __attribute__((ext_vector_type(8))) unsigned short u16x8;

#define BATCH 4
#define CH 512
#define NN 4096
#define CQ 64

__device__ __forceinline__ float bf2f(u16 v) {
    union { unsigned int u; float f; } x; x.u = ((unsigned int)v) << 16; return x.f;
}

// ---------------------------------------------------------------------------
// Input dtype detector (safety net): 0 = fp32 inputs, 1 = bf16 inputs.
// ---------------------------------------------------------------------------
__global__ __launch_bounds__(64) void detect_kernel(const u32* __restrict__ xw,
                                                    int* __restrict__ flag)
{
    const u32 w  = xw[threadIdx.x];
    const u32 ex = (w >> 23) & 0xFFu;
    const int plausible = (ex >= 100u && ex <= 132u) ? 1 : 0;
    const unsigned long long m = __ballot(plausible);
    if (threadIdx.x == 0) flag[0] = (__popcll(m) >= 48) ? 0 : 1;
}

// ---------------------------------------------------------------------------
// Projection GEMM (fp32 VALU, verified): outputs f16.
//   o <  64 : -> fT[b][n][o]      (f16, [N][CQ])
//   o < 128 : -> gT[b][n][o-64]   (f16, [N][CQ])
//   else    : -> hv[b][o-128][n]  (f16, [CH][N])
// ---------------------------------------------------------------------------
__global__ __launch_bounds__(256) void proj_kernel(
    const void* __restrict__ xin, const void* __restrict__ Wq,
    const void* __restrict__ Wk, const void* __restrict__ Wv,
    const int* __restrict__ flag,
    f16* __restrict__ fT, f16* __restrict__ gT, f16* __restrict__ hv)
{
    const int isbf = *flag;
    const int nb = blockIdx.x;
    const int rb = blockIdx.y;
    const int b  = blockIdx.z;
    const int n0 = nb * 64, o0 = rb * 64;
    const int t  = threadIdx.x;
    const int ty = t >> 4, tx = t & 15;

    __shared__ float Wl[64][68];
    __shared__ float Xl[64][68];

    float acc[4][4];
#pragma unroll
    for (int r = 0; r < 4; ++r)
#pragma unroll
        for (int q = 0; q < 4; ++q) acc[r][q] = 0.f;

    const int so = t >> 2;
    const int sk = (t & 3) * 16;

    const void* wsrc; int wrow;
    {
        const int go = o0 + so;
        if (go < 64)       { wsrc = Wq; wrow = go; }
        else if (go < 128) { wsrc = Wk; wrow = go - 64; }
        else               { wsrc = Wv; wrow = go - 128; }
    }

    for (int k0 = 0; k0 < CH; k0 += 64) {
        if (isbf) {
            {
                const u16* p = (const u16*)wsrc + (size_t)wrow * CH + k0 + sk;
                const u16x8 w0 = *(const u16x8*)p;
                const u16x8 w1 = *(const u16x8*)(p + 8);
#pragma unroll
                for (int e = 0; e < 8; ++e) Wl[sk + e][so] = bf2f(w0[e]);
#pragma unroll
                for (int e = 0; e < 8; ++e) Wl[sk + 8 + e][so] = bf2f(w1[e]);
            }
            {
                const u16* p = (const u16*)xin +
                               ((size_t)(b * CH + k0 + so)) * NN + n0 + sk;
                const u16x8 x0 = *(const u16x8*)p;
                const u16x8 x1 = *(const u16x8*)(p + 8);
                *(float4*)&Xl[so][sk] =
                    make_float4(bf2f(x0[0]), bf2f(x0[1]), bf2f(x0[2]), bf2f(x0[3]));
                *(float4*)&Xl[so][sk + 4] =
                    make_float4(bf2f(x0[4]), bf2f(x0[5]), bf2f(x0[6]), bf2f(x0[7]));
                *(float4*)&Xl[so][sk + 8] =
                    make_float4(bf2f(x1[0]), bf2f(x1[1]), bf2f(x1[2]), bf2f(x1[3]));
                *(float4*)&Xl[so][sk + 12] =
                    make_float4(bf2f(x1[4]), bf2f(x1[5]), bf2f(x1[6]), bf2f(x1[7]));
            }
        } else {
            {
                const float* p = (const float*)wsrc + (size_t)wrow * CH + k0 + sk;
                const float4 a0 = ((const float4*)p)[0];
                const float4 a1 = ((const float4*)p)[1];
                const float4 a2 = ((const float4*)p)[2];
                const float4 a3 = ((const float4*)p)[3];
                const float av[16] = {a0.x,a0.y,a0.z,a0.w, a1.x,a1.y,a1.z,a1.w,
                                      a2.x,a2.y,a2.z,a2.w, a3.x,a3.y,a3.z,a3.w};
#pragma unroll
                for (int e = 0; e < 16; ++e) Wl[sk + e][so] = av[e];
            }
            {
                const float* p = (const float*)xin +
                                 ((size_t)(b * CH + k0 + so)) * NN + n0 + sk;
                *(float4*)&Xl[so][sk]      = ((const float4*)p)[0];
                *(float4*)&Xl[so][sk + 4]  = ((const float4*)p)[1];
                *(float4*)&Xl[so][sk + 8]  = ((const float4*)p)[2];
                *(float4*)&Xl[so][sk + 12] = ((const float4*)p)[3];
            }
        }
        __syncthreads();
#pragma unroll 16
        for (int kk = 0; kk < 64; ++kk) {
            const float4 a  = *(const float4*)&Wl[kk][ty * 4];
            const float4 bv = *(const float4*)&Xl[kk][tx * 4];
            const float av[4] = {a.x, a.y, a.z, a.w};
            const float bb[4] = {bv.x, bv.y, bv.z, bv.w};
#pragma unroll
            for (int r = 0; r < 4; ++r)
#pragma unroll
                for (int q = 0; q < 4; ++q) acc[r][q] += av[r] * bb[q];
        }
        __syncthreads();
    }

#pragma unroll
    for (int r = 0; r < 4; ++r) {
        const int o = o0 + ty * 4 + r;
#pragma unroll
        for (int q = 0; q < 4; ++q) {
            const int n = n0 + tx * 4 + q;
            if (o < CQ) {
                fT[((size_t)b * NN + n) * CQ + o] = (f16)acc[r][q];
            } else if (o < 2 * CQ) {
                gT[((size_t)b * NN + n) * CQ + (o - CQ)] = (f16)acc[r][q];
            } else {
                hv[((size_t)b * CH + (o - 2 * CQ)) * NN + n] = (f16)acc[r][q];
            }
        }
    }
}

// ---------------------------------------------------------------------------
// MFMA flash attention, software-pipelined.
// Block = 8 waves (512 thr), 32 j-columns; i-tile 256; 2 blocks/CU.
// Pipeline: hv A-frags double-buffered (kc+2 ahead; steps 6/7 preload next
// iter's kc0/kc1); fT frags for iter+1 issued at PV start (no barrier-drain
// stall: every in-flight load lands >=400cy before the next __syncthreads).
// ---------------------------------------------------------------------------
__global__ __launch_bounds__(512, 4) void attn_mfma(
    const void* __restrict__ xin, const f16* __restrict__ fT,
    const f16* __restrict__ gT, const f16* __restrict__ hv,
    const void* __restrict__ gammap, const int* __restrict__ flag,
    float* __restrict__ out)
{
    const int isbf = *flag;
    const int bid  = blockIdx.x;                 // 0..511
    const int xcd  = bid & 7, slot = bid >> 3;   // slot 0..63
    const int b    = xcd >> 1;                   // 2 XCDs per batch
    const int jblk = ((xcd & 1) << 6) + slot;    // 0..127
    const int j0   = jblk * 32;
    const int t    = threadIdx.x;
    const int w    = t >> 6;                     // wave 0..7
    const int l    = t & 63;
    const int j16  = l & 15;
    const int h    = l >> 4;                     // 0..3

    __shared__ f16   Pp[32 * 256];               // 16 KB, swizzled pack of P
    __shared__ float wmax[8][2][16];
    __shared__ float wsum[8][2][16];

    // g B-fragments, resident whole kernel: [jb][kc]
    f16x8 gf[2][2];
#pragma unroll
    for (int jb = 0; jb < 2; ++jb)
#pragma unroll
        for (int kc = 0; kc < 2; ++kc)
            gf[jb][kc] = *(const f16x8*)(gT +
                ((size_t)b * NN + j0 + 16 * jb + j16) * CQ + 32 * kc + 8 * h);

    f32x4 oacc[4][2];                            // [cb][jb]
#pragma unroll
    for (int cb = 0; cb < 4; ++cb)
#pragma unroll
        for (int jb = 0; jb < 2; ++jb)
#pragma unroll
            for (int r = 0; r < 4; ++r) oacc[cb][jb][r] = 0.f;

    float m_run[2] = {-1e30f, -1e30f};
    float l_run[2] = {0.f, 0.f};

    const f16* fbase = fT + (size_t)b * NN * CQ;
    const f16* hbase = hv + (size_t)b * CH * NN;

    // ---- pipeline prologue ----
    f16x8 fa[2][2];                              // fT frags for current iter
    {
        const int irow0 = 32 * w + j16;
        fa[0][0] = *(const f16x8*)(fbase + (size_t)irow0 * CQ + 8 * h);
        fa[0][1] = *(const f16x8*)(fbase + (size_t)irow0 * CQ + 32 + 8 * h);
        fa[1][0] = *(const f16x8*)(fbase + (size_t)(irow0 + 16) * CQ + 8 * h);
        fa[1][1] = *(const f16x8*)(fbase + (size_t)(irow0 + 16) * CQ + 32 + 8 * h);
    }
    f16x8 aA[4], aB[4];                          // hv A-frag double buffer

#define LDA(BUF, KC, I0BASE)                                                  \
    {                                                                         \
        _Pragma("unroll")                                                     \
        for (int cb = 0; cb < 4; ++cb)                                        \
            BUF[cb] = *(const f16x8*)(hbase +                                 \
                (size_t)(64 * w + 16 * cb + j16) * NN +                       \
                (I0BASE) + 32 * (KC) + 8 * h);                                \
    }

#define PVST(BUF, KC)                                                         \
    {                                                                         \
        const int sw0 = (4 * (KC) + h) ^ j16;                                 \
        const f16x8 pf0 = *(const f16x8*)&Pp[j16 * 256 + sw0 * 8];            \
        const f16x8 pf1 = *(const f16x8*)&Pp[(16 + j16) * 256 + sw0 * 8];     \
        __builtin_amdgcn_s_setprio(1);                                        \
        _Pragma("unroll")                                                     \
        for (int cb = 0; cb < 4; ++cb) {                                      \
            oacc[cb][0] = __builtin_amdgcn_mfma_f32_16x16x32_f16(             \
                              BUF[cb], pf0, oacc[cb][0], 0, 0, 0);            \
            oacc[cb][1] = __builtin_amdgcn_mfma_f32_16x16x32_f16(             \
                              BUF[cb], pf1, oacc[cb][1], 0, 0, 0);            \
        }                                                                     \
        __builtin_amdgcn_s_setprio(0);                                        \
    }

    LDA(aA, 0, 0);
    LDA(aB, 1, 0);

    for (int it = 0; it < 16; ++it) {
        const int i0 = it * 256;

        // ---- QK^T: S[32 i x 32 j] for this wave's i-slice ----
        f32x4 s[2][2];
#pragma unroll
        for (int ib = 0; ib < 2; ++ib)
#pragma unroll
            for (int jb = 0; jb < 2; ++jb)
#pragma unroll
                for (int r = 0; r < 4; ++r) s[ib][jb][r] = 0.f;

        __builtin_amdgcn_s_setprio(1);
#pragma unroll
        for (int ib = 0; ib < 2; ++ib)
#pragma unroll
            for (int jb = 0; jb < 2; ++jb) {
                s[ib][jb] = __builtin_amdgcn_mfma_f32_16x16x32_f16(
                                fa[ib][0], gf[jb][0], s[ib][jb], 0, 0, 0);
                s[ib][jb] = __builtin_amdgcn_mfma_f32_16x16x32_f16(
                                fa[ib][1], gf[jb][1], s[ib][jb], 0, 0, 0);
            }
        __builtin_amdgcn_s_setprio(0);

        // ---- per-column max (over rows = i) ----
        float pmax[2];
#pragma unroll
        for (int jb = 0; jb < 2; ++jb) {
            float m0 = fmaxf(fmaxf(s[0][jb][0], s[0][jb][1]),
                             fmaxf(s[0][jb][2], s[0][jb][3]));
            float m1 = fmaxf(fmaxf(s[1][jb][0], s[1][jb][1]),
                             fmaxf(s[1][jb][2], s[1][jb][3]));
            float mm = fmaxf(m0, m1);
            mm = fmaxf(mm, __shfl_xor(mm, 16));
            mm = fmaxf(mm, __shfl_xor(mm, 32));
            pmax[jb] = mm;
        }
        if (h == 0) { wmax[w][0][j16] = pmax[0]; wmax[w][1][j16] = pmax[1]; }
        __syncthreads();                          // barrier 1

        float m_new[2], sc[2];
#pragma unroll
        for (int jb = 0; jb < 2; ++jb) {
            float tm = wmax[0][jb][j16];
#pragma unroll
            for (int w2 = 1; w2 < 8; ++w2) tm = fmaxf(tm, wmax[w2][jb][j16]);
            m_new[jb] = fmaxf(m_run[jb], tm);
            sc[jb]    = __expf(m_run[jb] - m_new[jb]);
            m_run[jb] = m_new[jb];
        }

        // ---- P = exp(S - m): pack f16 into LDS + partial sums ----
        float psum[2] = {0.f, 0.f};
#pragma unroll
        for (int ib = 0; ib < 2; ++ib) {
#pragma unroll
            for (int jb = 0; jb < 2; ++jb) {
                const float p0 = __expf(s[ib][jb][0] - m_new[jb]);
                const float p1 = __expf(s[ib][jb][1] - m_new[jb]);
                const float p2 = __expf(s[ib][jb][2] - m_new[jb]);
                const float p3 = __expf(s[ib][jb][3] - m_new[jb]);
                psum[jb] += (p0 + p1) + (p2 + p3);
                f16x4 v4;
                v4[0] = (f16)p0; v4[1] = (f16)p1; v4[2] = (f16)p2; v4[3] = (f16)p3;
                const int jloc = 16 * jb + j16;
                const int sw   = (4 * w + 2 * ib + (h >> 1)) ^ j16;
                *(f16x4*)&Pp[jloc * 256 + sw * 8 + (h & 1) * 4] = v4;
            }
        }
#pragma unroll
        for (int jb = 0; jb < 2; ++jb) {
            psum[jb] += __shfl_xor(psum[jb], 16);
            psum[jb] += __shfl_xor(psum[jb], 32);
        }
        if (h == 0) { wsum[w][0][j16] = psum[0]; wsum[w][1][j16] = psum[1]; }

        // ---- rescale O by exp(m_old - m_new) ----
#pragma unroll
        for (int cb = 0; cb < 4; ++cb)
#pragma unroll
            for (int jb = 0; jb < 2; ++jb)
#pragma unroll
                for (int r = 0; r < 4; ++r) oacc[cb][jb][r] *= sc[jb];

        __syncthreads();                          // barrier 2 (P + sums ready)

#pragma unroll
        for (int jb = 0; jb < 2; ++jb) {
            float ts = 0.f;
#pragma unroll
            for (int w2 = 0; w2 < 8; ++w2) ts += wsum[w2][jb][j16];
            l_run[jb] = l_run[jb] * sc[jb] + ts;
        }

        // ---- PV phase, pipelined ----
        const int i0n = (it < 15) ? (i0 + 256) : 0;
        {   // fT frags for next iter: ~800cy ahead of use, no barrier in between
            const int irow0 = i0n + 32 * w + j16;
            fa[0][0] = *(const f16x8*)(fbase + (size_t)irow0 * CQ + 8 * h);
            fa[0][1] = *(const f16x8*)(fbase + (size_t)irow0 * CQ + 32 + 8 * h);
            fa[1][0] = *(const f16x8*)(fbase + (size_t)(irow0 + 16) * CQ + 8 * h);
            fa[1][1] = *(const f16x8*)(fbase + (size_t)(irow0 + 16) * CQ + 32 + 8 * h);
        }
        PVST(aA, 0); LDA(aA, 2, i0);
        PVST(aB, 1); LDA(aB, 3, i0);
        PVST(aA, 2); LDA(aA, 4, i0);
        PVST(aB, 3); LDA(aB, 5, i0);
        PVST(aA, 4); LDA(aA, 6, i0);
        PVST(aB, 5); LDA(aB, 7, i0);
        PVST(aA, 6); LDA(aA, 0, i0n);
        PVST(aB, 7); LDA(aB, 1, i0n);
    }

    // ---- epilogue: out = gamma * O / l + x  (fp32 out) ----
    float gam;
    if (isbf) gam = bf2f(((const u16*)gammap)[0]);
    else      gam = ((const float*)gammap)[0];

    const float inv0 = gam / l_run[0];
    const float inv1 = gam / l_run[1];

#pragma unroll
    for (int cb = 0; cb < 4; ++cb) {
#pragma unroll
        for (int jb = 0; jb < 2; ++jb) {
            const float invj = jb ? inv1 : inv0;
            const int j = j0 + 16 * jb + j16;
#pragma unroll
            for (int r = 0; r < 4; ++r) {
                const int c = 64 * w + 16 * cb + 4 * h + r;
                const size_t idx = ((size_t)b * CH + c) * NN + j;
                float xv;
                if (isbf) xv = bf2f(((const u16*)xin)[idx]);
                else      xv = ((const float*)xin)[idx];
                out[idx] = oacc[cb][jb][r] * invj + xv;
            }
        }
    }
#undef LDA
#undef PVST
}

extern "C" void kernel_launch(void* const* d_in, const int* in_sizes, int n_in,
                              void* d_out, int out_size, void* d_ws, size_t ws_size,
                              hipStream_t stream)
{
    // ws layout: [flag 256B][fT f16 2MB][gT f16 2MB][hv f16 8MB]
    int* flag = (int*)d_ws;
    f16* fT = (f16*)((char*)d_ws + 256);            // [B][N][CQ]
    f16* gT = fT + (size_t)BATCH * NN * CQ;         // [B][N][CQ]
    f16* hv = gT + (size_t)BATCH * NN * CQ;         // [B][CH][N]

    detect_kernel<<<1, 64, 0, stream>>>((const u32*)d_in[0], flag);

    dim3 pgrid(64, 10, BATCH);
    proj_kernel<<<pgrid, 256, 0, stream>>>(d_in[0], d_in[1], d_in[2], d_in[3],
                                           flag, fT, gT, hv);
    attn_mfma<<<512, 512, 0, stream>>>(d_in[0], fT, gT, hv, d_in[4],
                                       flag, (float*)d_out);
}

// Round 6
// 435.258 us; speedup vs baseline: 1.1364x; 1.1364x over previous
//
#include <hip/hip_runtime.h>
#include <hip/hip_bf16.h>

typedef unsigned short u16;
typedef unsigned int   u32;
typedef _Float16 f16;
typedef __attribute__((ext_vector_type(8))) _Float16 f16x8;
typedef __attribute__((ext_vector_type(4))) _Float16 f16x4;
typedef __attribute__((ext_vector_type(4))) float    f32x4;
typedef __attribute__((ext_vector_type(8))) unsigned short u16x8;

#define BATCH 4
#define CH 512
#define NN 4096
#define CQ 64

__device__ __forceinline__ float bf2f(u16 v) {
    union { unsigned int u; float f; } x; x.u = ((unsigned int)v) << 16; return x.f;
}

// ---------------------------------------------------------------------------
// Input dtype detector (safety net): 0 = fp32 inputs, 1 = bf16 inputs.
// ---------------------------------------------------------------------------
__global__ __launch_bounds__(64) void detect_kernel(const u32* __restrict__ xw,
                                                    int* __restrict__ flag)
{
    const u32 w  = xw[threadIdx.x];
    const u32 ex = (w >> 23) & 0xFFu;
    const int plausible = (ex >= 100u && ex <= 132u) ? 1 : 0;
    const unsigned long long m = __ballot(plausible);
    if (threadIdx.x == 0) flag[0] = (__popcll(m) >= 48) ? 0 : 1;
}

// ---------------------------------------------------------------------------
// Projection GEMM (fp32 VALU, verified): outputs f16.
//   o <  64 : -> fT[b][n][o]      (f16, [N][CQ])
//   o < 128 : -> gT[b][n][o-64]   (f16, [N][CQ])
//   else    : -> hv[b][o-128][n]  (f16, [CH][N])
// ---------------------------------------------------------------------------
__global__ __launch_bounds__(256) void proj_kernel(
    const void* __restrict__ xin, const void* __restrict__ Wq,
    const void* __restrict__ Wk, const void* __restrict__ Wv,
    const int* __restrict__ flag,
    f16* __restrict__ fT, f16* __restrict__ gT, f16* __restrict__ hv)
{
    const int isbf = *flag;
    const int nb = blockIdx.x;
    const int rb = blockIdx.y;
    const int b  = blockIdx.z;
    const int n0 = nb * 64, o0 = rb * 64;
    const int t  = threadIdx.x;
    const int ty = t >> 4, tx = t & 15;

    __shared__ float Wl[64][68];
    __shared__ float Xl[64][68];

    float acc[4][4];
#pragma unroll
    for (int r = 0; r < 4; ++r)
#pragma unroll
        for (int q = 0; q < 4; ++q) acc[r][q] = 0.f;

    const int so = t >> 2;
    const int sk = (t & 3) * 16;

    const void* wsrc; int wrow;
    {
        const int go = o0 + so;
        if (go < 64)       { wsrc = Wq; wrow = go; }
        else if (go < 128) { wsrc = Wk; wrow = go - 64; }
        else               { wsrc = Wv; wrow = go - 128; }
    }

    for (int k0 = 0; k0 < CH; k0 += 64) {
        if (isbf) {
            {
                const u16* p = (const u16*)wsrc + (size_t)wrow * CH + k0 + sk;
                const u16x8 w0 = *(const u16x8*)p;
                const u16x8 w1 = *(const u16x8*)(p + 8);
#pragma unroll
                for (int e = 0; e < 8; ++e) Wl[sk + e][so] = bf2f(w0[e]);
#pragma unroll
                for (int e = 0; e < 8; ++e) Wl[sk + 8 + e][so] = bf2f(w1[e]);
            }
            {
                const u16* p = (const u16*)xin +
                               ((size_t)(b * CH + k0 + so)) * NN + n0 + sk;
                const u16x8 x0 = *(const u16x8*)p;
                const u16x8 x1 = *(const u16x8*)(p + 8);
                *(float4*)&Xl[so][sk] =
                    make_float4(bf2f(x0[0]), bf2f(x0[1]), bf2f(x0[2]), bf2f(x0[3]));
                *(float4*)&Xl[so][sk + 4] =
                    make_float4(bf2f(x0[4]), bf2f(x0[5]), bf2f(x0[6]), bf2f(x0[7]));
                *(float4*)&Xl[so][sk + 8] =
                    make_float4(bf2f(x1[0]), bf2f(x1[1]), bf2f(x1[2]), bf2f(x1[3]));
                *(float4*)&Xl[so][sk + 12] =
                    make_float4(bf2f(x1[4]), bf2f(x1[5]), bf2f(x1[6]), bf2f(x1[7]));
            }
        } else {
            {
                const float* p = (const float*)wsrc + (size_t)wrow * CH + k0 + sk;
                const float4 a0 = ((const float4*)p)[0];
                const float4 a1 = ((const float4*)p)[1];
                const float4 a2 = ((const float4*)p)[2];
                const float4 a3 = ((const float4*)p)[3];
                const float av[16] = {a0.x,a0.y,a0.z,a0.w, a1.x,a1.y,a1.z,a1.w,
                                      a2.x,a2.y,a2.z,a2.w, a3.x,a3.y,a3.z,a3.w};
#pragma unroll
                for (int e = 0; e < 16; ++e) Wl[sk + e][so] = av[e];
            }
            {
                const float* p = (const float*)xin +
                                 ((size_t)(b * CH + k0 + so)) * NN + n0 + sk;
                *(float4*)&Xl[so][sk]      = ((const float4*)p)[0];
                *(float4*)&Xl[so][sk + 4]  = ((const float4*)p)[1];
                *(float4*)&Xl[so][sk + 8]  = ((const float4*)p)[2];
                *(float4*)&Xl[so][sk + 12] = ((const float4*)p)[3];
            }
        }
        __syncthreads();
#pragma unroll 16
        for (int kk = 0; kk < 64; ++kk) {
            const float4 a  = *(const float4*)&Wl[kk][ty * 4];
            const float4 bv = *(const float4*)&Xl[kk][tx * 4];
            const float av[4] = {a.x, a.y, a.z, a.w};
            const float bb[4] = {bv.x, bv.y, bv.z, bv.w};
#pragma unroll
            for (int r = 0; r < 4; ++r)
#pragma unroll
                for (int q = 0; q < 4; ++q) acc[r][q] += av[r] * bb[q];
        }
        __syncthreads();
    }

#pragma unroll
    for (int r = 0; r < 4; ++r) {
        const int o = o0 + ty * 4 + r;
#pragma unroll
        for (int q = 0; q < 4; ++q) {
            const int n = n0 + tx * 4 + q;
            if (o < CQ) {
                fT[((size_t)b * NN + n) * CQ + o] = (f16)acc[r][q];
            } else if (o < 2 * CQ) {
                gT[((size_t)b * NN + n) * CQ + (o - CQ)] = (f16)acc[r][q];
            } else {
                hv[((size_t)b * CH + (o - 2 * CQ)) * NN + n] = (f16)acc[r][q];
            }
        }
    }
}

// ---------------------------------------------------------------------------
// MFMA flash attention, software-pipelined.
// Block = 8 waves (512 thr), 32 j-columns; i-tile 256; target 2 blocks/CU.
// __launch_bounds__(512, 2): cap >=128 VGPRs so the dist-2 hv double-buffer
// and cross-iteration fT prefetch live in registers (round 5's (512,4) forced
// a 64-VGPR cap -> 100MB of scratch spill, the regression).
// ---------------------------------------------------------------------------
__global__ __launch_bounds__(512, 2) void attn_mfma(
    const void* __restrict__ xin, const f16* __restrict__ fT,
    const f16* __restrict__ gT, const f16* __restrict__ hv,
    const void* __restrict__ gammap, const int* __restrict__ flag,
    float* __restrict__ out)
{
    const int isbf = *flag;
    const int bid  = blockIdx.x;                 // 0..511
    const int xcd  = bid & 7, slot = bid >> 3;   // slot 0..63
    const int b    = xcd >> 1;                   // 2 XCDs per batch
    const int jblk = ((xcd & 1) << 6) + slot;    // 0..127
    const int j0   = jblk * 32;
    const int t    = threadIdx.x;
    const int w    = t >> 6;                     // wave 0..7
    const int l    = t & 63;
    const int j16  = l & 15;
    const int h    = l >> 4;                     // 0..3

    __shared__ f16   Pp[32 * 256];               // 16 KB, swizzled pack of P
    __shared__ float wmax[8][2][16];
    __shared__ float wsum[8][2][16];

    // g B-fragments, resident whole kernel: [jb][kc]
    f16x8 gf[2][2];
#pragma unroll
    for (int jb = 0; jb < 2; ++jb)
#pragma unroll
        for (int kc = 0; kc < 2; ++kc)
            gf[jb][kc] = *(const f16x8*)(gT +
                ((size_t)b * NN + j0 + 16 * jb + j16) * CQ + 32 * kc + 8 * h);

    f32x4 oacc[4][2];                            // [cb][jb]
#pragma unroll
    for (int cb = 0; cb < 4; ++cb)
#pragma unroll
        for (int jb = 0; jb < 2; ++jb)
#pragma unroll
            for (int r = 0; r < 4; ++r) oacc[cb][jb][r] = 0.f;

    float m_run[2] = {-1e30f, -1e30f};
    float l_run[2] = {0.f, 0.f};

    const f16* fbase = fT + (size_t)b * NN * CQ;
    const f16* hbase = hv + (size_t)b * CH * NN;

    // ---- pipeline prologue ----
    f16x8 fa[2][2];                              // fT frags for current iter
    {
        const int irow0 = 32 * w + j16;
        fa[0][0] = *(const f16x8*)(fbase + (size_t)irow0 * CQ + 8 * h);
        fa[0][1] = *(const f16x8*)(fbase + (size_t)irow0 * CQ + 32 + 8 * h);
        fa[1][0] = *(const f16x8*)(fbase + (size_t)(irow0 + 16) * CQ + 8 * h);
        fa[1][1] = *(const f16x8*)(fbase + (size_t)(irow0 + 16) * CQ + 32 + 8 * h);
    }
    f16x8 aA[4], aB[4];                          // hv A-frag double buffer

#define LDA(BUF, KC, I0BASE)                                                  \
    {                                                                         \
        _Pragma("unroll")                                                     \
        for (int cb = 0; cb < 4; ++cb)                                        \
            BUF[cb] = *(const f16x8*)(hbase +                                 \
                (size_t)(64 * w + 16 * cb + j16) * NN +                       \
                (I0BASE) + 32 * (KC) + 8 * h);                                \
    }

#define PVST(BUF, KC)                                                         \
    {                                                                         \
        const int sw0 = (4 * (KC) + h) ^ j16;                                 \
        const f16x8 pf0 = *(const f16x8*)&Pp[j16 * 256 + sw0 * 8];            \
        const f16x8 pf1 = *(const f16x8*)&Pp[(16 + j16) * 256 + sw0 * 8];     \
        __builtin_amdgcn_s_setprio(1);                                        \
        _Pragma("unroll")                                                     \
        for (int cb = 0; cb < 4; ++cb) {                                      \
            oacc[cb][0] = __builtin_amdgcn_mfma_f32_16x16x32_f16(             \
                              BUF[cb], pf0, oacc[cb][0], 0, 0, 0);            \
            oacc[cb][1] = __builtin_amdgcn_mfma_f32_16x16x32_f16(             \
                              BUF[cb], pf1, oacc[cb][1], 0, 0, 0);            \
        }                                                                     \
        __builtin_amdgcn_s_setprio(0);                                        \
    }

    LDA(aA, 0, 0);
    LDA(aB, 1, 0);

    for (int it = 0; it < 16; ++it) {
        const int i0 = it * 256;

        // ---- QK^T: S[32 i x 32 j] for this wave's i-slice ----
        f32x4 s[2][2];
#pragma unroll
        for (int ib = 0; ib < 2; ++ib)
#pragma unroll
            for (int jb = 0; jb < 2; ++jb)
#pragma unroll
                for (int r = 0; r < 4; ++r) s[ib][jb][r] = 0.f;

        __builtin_amdgcn_s_setprio(1);
#pragma unroll
        for (int ib = 0; ib < 2; ++ib)
#pragma unroll
            for (int jb = 0; jb < 2; ++jb) {
                s[ib][jb] = __builtin_amdgcn_mfma_f32_16x16x32_f16(
                                fa[ib][0], gf[jb][0], s[ib][jb], 0, 0, 0);
                s[ib][jb] = __builtin_amdgcn_mfma_f32_16x16x32_f16(
                                fa[ib][1], gf[jb][1], s[ib][jb], 0, 0, 0);
            }
        __builtin_amdgcn_s_setprio(0);

        // ---- per-column max (over rows = i) ----
        float pmax[2];
#pragma unroll
        for (int jb = 0; jb < 2; ++jb) {
            float m0 = fmaxf(fmaxf(s[0][jb][0], s[0][jb][1]),
                             fmaxf(s[0][jb][2], s[0][jb][3]));
            float m1 = fmaxf(fmaxf(s[1][jb][0], s[1][jb][1]),
                             fmaxf(s[1][jb][2], s[1][jb][3]));
            float mm = fmaxf(m0, m1);
            mm = fmaxf(mm, __shfl_xor(mm, 16));
            mm = fmaxf(mm, __shfl_xor(mm, 32));
            pmax[jb] = mm;
        }
        if (h == 0) { wmax[w][0][j16] = pmax[0]; wmax[w][1][j16] = pmax[1]; }
        __syncthreads();                          // barrier 1

        float m_new[2], sc[2];
#pragma unroll
        for (int jb = 0; jb < 2; ++jb) {
            float tm = wmax[0][jb][j16];
#pragma unroll
            for (int w2 = 1; w2 < 8; ++w2) tm = fmaxf(tm, wmax[w2][jb][j16]);
            m_new[jb] = fmaxf(m_run[jb], tm);
            sc[jb]    = __expf(m_run[jb] - m_new[jb]);
            m_run[jb] = m_new[jb];
        }

        // ---- P = exp(S - m): pack f16 into LDS + partial sums ----
        float psum[2] = {0.f, 0.f};
#pragma unroll
        for (int ib = 0; ib < 2; ++ib) {
#pragma unroll
            for (int jb = 0; jb < 2; ++jb) {
                const float p0 = __expf(s[ib][jb][0] - m_new[jb]);
                const float p1 = __expf(s[ib][jb][1] - m_new[jb]);
                const float p2 = __expf(s[ib][jb][2] - m_new[jb]);
                const float p3 = __expf(s[ib][jb][3] - m_new[jb]);
                psum[jb] += (p0 + p1) + (p2 + p3);
                f16x4 v4;
                v4[0] = (f16)p0; v4[1] = (f16)p1; v4[2] = (f16)p2; v4[3] = (f16)p3;
                const int jloc = 16 * jb + j16;
                const int sw   = (4 * w + 2 * ib + (h >> 1)) ^ j16;
                *(f16x4*)&Pp[jloc * 256 + sw * 8 + (h & 1) * 4] = v4;
            }
        }
#pragma unroll
        for (int jb = 0; jb < 2; ++jb) {
            psum[jb] += __shfl_xor(psum[jb], 16);
            psum[jb] += __shfl_xor(psum[jb], 32);
        }
        if (h == 0) { wsum[w][0][j16] = psum[0]; wsum[w][1][j16] = psum[1]; }

        // ---- rescale O by exp(m_old - m_new) ----
#pragma unroll
        for (int cb = 0; cb < 4; ++cb)
#pragma unroll
            for (int jb = 0; jb < 2; ++jb)
#pragma unroll
                for (int r = 0; r < 4; ++r) oacc[cb][jb][r] *= sc[jb];

        __syncthreads();                          // barrier 2 (P + sums ready)

#pragma unroll
        for (int jb = 0; jb < 2; ++jb) {
            float ts = 0.f;
#pragma unroll
            for (int w2 = 0; w2 < 8; ++w2) ts += wsum[w2][jb][j16];
            l_run[jb] = l_run[jb] * sc[jb] + ts;
        }

        // ---- PV phase, pipelined ----
        const int i0n = (it < 15) ? (i0 + 256) : 0;
        {   // fT frags for next iter: ~800cy ahead of use, no barrier in between
            const int irow0 = i0n + 32 * w + j16;
            fa[0][0] = *(const f16x8*)(fbase + (size_t)irow0 * CQ + 8 * h);
            fa[0][1] = *(const f16x8*)(fbase + (size_t)irow0 * CQ + 32 + 8 * h);
            fa[1][0] = *(const f16x8*)(fbase + (size_t)(irow0 + 16) * CQ + 8 * h);
            fa[1][1] = *(const f16x8*)(fbase + (size_t)(irow0 + 16) * CQ + 32 + 8 * h);
        }
        PVST(aA, 0); LDA(aA, 2, i0);
        PVST(aB, 1); LDA(aB, 3, i0);
        PVST(aA, 2); LDA(aA, 4, i0);
        PVST(aB, 3); LDA(aB, 5, i0);
        PVST(aA, 4); LDA(aA, 6, i0);
        PVST(aB, 5); LDA(aB, 7, i0);
        PVST(aA, 6); LDA(aA, 0, i0n);
        PVST(aB, 7); LDA(aB, 1, i0n);
    }

    // ---- epilogue: out = gamma * O / l + x  (fp32 out) ----
    float gam;
    if (isbf) gam = bf2f(((const u16*)gammap)[0]);
    else      gam = ((const float*)gammap)[0];

    const float inv0 = gam / l_run[0];
    const float inv1 = gam / l_run[1];

#pragma unroll
    for (int cb = 0; cb < 4; ++cb) {
#pragma unroll
        for (int jb = 0; jb < 2; ++jb) {
            const float invj = jb ? inv1 : inv0;
            const int j = j0 + 16 * jb + j16;
#pragma unroll
            for (int r = 0; r < 4; ++r) {
                const int c = 64 * w + 16 * cb + 4 * h + r;
                const size_t idx = ((size_t)b * CH + c) * NN + j;
                float xv;
                if (isbf) xv = bf2f(((const u16*)xin)[idx]);
                else      xv = ((const float*)xin)[idx];
                out[idx] = oacc[cb][jb][r] * invj + xv;
            }
        }
    }
#undef LDA
#undef PVST
}

extern "C" void kernel_launch(void* const* d_in, const int* in_sizes, int n_in,
                              void* d_out, int out_size, void* d_ws, size_t ws_size,
                              hipStream_t stream)
{
    // ws layout: [flag 256B][fT f16 2MB][gT f16 2MB][hv f16 8MB]
    int* flag = (int*)d_ws;
    f16* fT = (f16*)((char*)d_ws + 256);            // [B][N][CQ]
    f16* gT = fT + (size_t)BATCH * NN * CQ;         // [B][N][CQ]
    f16* hv = gT + (size_t)BATCH * NN * CQ;         // [B][CH][N]

    detect_kernel<<<1, 64, 0, stream>>>((const u32*)d_in[0], flag);

    dim3 pgrid(64, 10, BATCH);
    proj_kernel<<<pgrid, 256, 0, stream>>>(d_in[0], d_in[1], d_in[2], d_in[3],
                                           flag, fT, gT, hv);
    attn_mfma<<<512, 512, 0, stream>>>(d_in[0], fT, gT, hv, d_in[4],
                                       flag, (float*)d_out);
}